// Round 3
// baseline (379.786 us; speedup 1.0000x reference)
//
#include <hip/hip_runtime.h>
#include <hip/hip_bf16.h>

#define B_   32
#define CIN  96
#define COUT 96
#define NP   3136
#define NE   8
#define HIDD 576

typedef short bf16x8 __attribute__((ext_vector_type(8)));
typedef float f32x4 __attribute__((ext_vector_type(4)));

__device__ __forceinline__ unsigned short f2bf(float f) {
  __hip_bfloat16 h = __float2bfloat16(f);
  unsigned short u; __builtin_memcpy(&u, &h, 2); return u;
}
__device__ __forceinline__ float bf2f(unsigned short u) {
  unsigned int v = ((unsigned int)u) << 16;
  float f; __builtin_memcpy(&f, &v, 4); return f;
}

// ---------------- kernel 1: transpose x -> x_t[b][p][c] bf16, + channel sums --
__global__ __launch_bounds__(256) void k_transpose(const float* __restrict__ x,
                                                   unsigned short* __restrict__ xt,
                                                   float* __restrict__ xmean) {
  __shared__ float tile[CIN][65];
  int bi = blockIdx.x; int b = bi / 49, pt = bi % 49; int p0 = pt * 64;
  int t = threadIdx.x;
  for (int j = t; j < CIN * 64; j += 256) {
    int c = j >> 6, pi = j & 63;
    tile[c][pi] = x[((size_t)(b * CIN + c)) * NP + p0 + pi];
  }
  __syncthreads();
  if (t < CIN) {
    float s = 0.f;
    for (int i = 0; i < 64; ++i) s += tile[t][i];
    atomicAdd(xmean + b * CIN + t, s);
  }
  for (int j = t; j < 64 * CIN; j += 256) {
    int p = j / CIN, c = j % CIN;
    xt[((size_t)(b * NP + p0 + p)) * CIN + c] = f2bf(tile[c][p]);
  }
}

// ---------------- kernel 2: routers r1 (expand) and r_blk (project) ----------
__global__ __launch_bounds__(64) void k_router1(const float* __restrict__ xmean,
    const float* __restrict__ wr1, const float* __restrict__ br1,
    const float* __restrict__ wr3, const float* __restrict__ br3,
    float* __restrict__ r1, float* __restrict__ rblk) {
  int bi = blockIdx.x; int lane = threadIdx.x;
  const float* wr; const float* br; float* dst; int id;
  if (bi < 256) { wr = wr1; br = br1; dst = r1;   id = bi; }
  else          { wr = wr3; br = br3; dst = rblk; id = bi - 256; }
  int b = id >> 3, e = id & 7;
  float s = 0.f;
  for (int c = lane; c < CIN; c += 64)
    s += xmean[b * CIN + c] * (1.0f / NP) * wr[e * CIN + c];
  s += __shfl_xor(s, 1);  s += __shfl_xor(s, 2);  s += __shfl_xor(s, 4);
  s += __shfl_xor(s, 8);  s += __shfl_xor(s, 16); s += __shfl_xor(s, 32);
  if (lane == 0) dst[id] = 1.0f / (1.0f + __expf(-(s + br[e])));
}

// ---------------- kernel 3: BN scale/bias precompute -------------------------
__global__ __launch_bounds__(256) void k_bnprep(
    const float* g1, const float* bt1, const float* m1, const float* v1,
    const float* g2, const float* bt2, const float* m2, const float* v2,
    const float* g3, const float* bt3, const float* m3, const float* v3,
    float* sc1, float* bi1, float* sc2, float* bi2, float* sc3, float* bi3) {
  int i = blockIdx.x * 256 + threadIdx.x;
  if (i < HIDD) {
    float s = g1[i] * rsqrtf(v1[i] + 1e-5f); sc1[i] = s; bi1[i] = bt1[i] - m1[i] * s;
  } else if (i < 2 * HIDD) {
    int c = i - HIDD;
    float s = g2[c] * rsqrtf(v2[c] + 1e-5f); sc2[c] = s; bi2[c] = bt2[c] - m2[c] * s;
  } else if (i < 2 * HIDD + COUT) {
    int c = i - 2 * HIDD;
    float s = g3[c] * rsqrtf(v3[c] + 1e-5f); sc3[c] = s; bi3[c] = bt3[c] - m3[c] * s;
  }
}

// ---------------- kernel 4: mix expert weights -> bf16 -----------------------
__global__ __launch_bounds__(256) void k_mixw(
    const float* __restrict__ w1, const float* __restrict__ r1, unsigned short* __restrict__ w1c,
    const float* __restrict__ w3, const float* __restrict__ rblk, unsigned short* __restrict__ w3c) {
  __shared__ float rsh[256];
  int bi = blockIdx.x; int t = threadIdx.x;
  const float* w; const float* r; unsigned short* dst; int oc0;
  if (bi < 216) { w = w1; r = r1;   dst = w1c; oc0 = bi * 256; }
  else          { w = w3; r = rblk; dst = w3c; oc0 = (bi - 216) * 256; }
  rsh[t] = r[t];
  __syncthreads();
  int oc = oc0 + t;
  float wv[NE];
#pragma unroll
  for (int e = 0; e < NE; ++e) wv[e] = w[(size_t)e * 55296 + oc];
  for (int b = 0; b < B_; ++b) {
    float a = 0.f;
#pragma unroll
    for (int e = 0; e < NE; ++e) a += rsh[b * 8 + e] * wv[e];
    dst[(size_t)b * 55296 + oc] = f2bf(a);
  }
}

// ---------------- kernel 5: expand GEMM (bf16 MFMA) + BN + ReLU6 + ysum ------
// Y[b][o][p] = relu6(bn1( sum_c w1c[b][o][c] * x_t[b][p][c] ))
__global__ __launch_bounds__(256) void k_expand(const unsigned short* __restrict__ xt,
    const unsigned short* __restrict__ w1c, const float* __restrict__ sc1,
    const float* __restrict__ bi1, unsigned short* __restrict__ y,
    float* __restrict__ ysum) {
  __shared__ unsigned short As[64 * 104];
  __shared__ unsigned short Bs[64 * 104];
  int t = threadIdx.x;
  int p0 = blockIdx.x * 64, o0 = blockIdx.y * 64, b = blockIdx.z;
  const unsigned short* ag = w1c + (size_t)b * 55296 + (size_t)o0 * 96;
  const unsigned short* bg = xt + ((size_t)b * NP + p0) * 96;
  for (int j = t; j < 768; j += 256) {
    int r = j / 12, ch = j % 12;
    *(int4*)(As + r * 104 + ch * 8) = *(const int4*)(ag + r * 96 + ch * 8);
    *(int4*)(Bs + r * 104 + ch * 8) = *(const int4*)(bg + r * 96 + ch * 8);
  }
  __syncthreads();
  int lane = t & 63, wv = t >> 6;
  int m = lane & 15, q = lane >> 4;
  f32x4 acc[4];
#pragma unroll
  for (int nt = 0; nt < 4; ++nt) acc[nt] = 0.f;
#pragma unroll
  for (int kk = 0; kk < 3; ++kk) {
    bf16x8 af = *(const bf16x8*)(As + (wv * 16 + m) * 104 + kk * 32 + q * 8);
#pragma unroll
    for (int nt = 0; nt < 4; ++nt) {
      bf16x8 bfb = *(const bf16x8*)(Bs + (nt * 16 + m) * 104 + kk * 32 + q * 8);
      acc[nt] = __builtin_amdgcn_mfma_f32_16x16x32_bf16(af, bfb, acc[nt], 0, 0, 0);
    }
  }
#pragma unroll
  for (int i = 0; i < 4; ++i) {
    int ol = wv * 16 + q * 4 + i; int o = o0 + ol;
    float sc = sc1[o], bb = bi1[o];
    float rs = 0.f;
    size_t base = ((size_t)(b * HIDD + o)) * NP + p0;
#pragma unroll
    for (int nt = 0; nt < 4; ++nt) {
      float v = acc[nt][i] * sc + bb;
      v = fminf(fmaxf(v, 0.f), 6.f);
      y[base + nt * 16 + m] = f2bf(v);
      rs += v;
    }
    rs += __shfl_xor(rs, 1); rs += __shfl_xor(rs, 2);
    rs += __shfl_xor(rs, 4); rs += __shfl_xor(rs, 8);
    if (m == 0) atomicAdd(ysum + b * HIDD + o, rs);
  }
}

// ---------------- kernel 6: router r2 (depthwise) ----------------------------
__global__ __launch_bounds__(64) void k_router2(const float* __restrict__ ysum,
    const float* __restrict__ wr2, const float* __restrict__ br2, float* __restrict__ r2) {
  int id = blockIdx.x; int lane = threadIdx.x;
  int b = id >> 3, e = id & 7;
  float s = 0.f;
  for (int h = lane; h < HIDD; h += 64)
    s += ysum[b * HIDD + h] * (1.0f / NP) * wr2[e * HIDD + h];
  s += __shfl_xor(s, 1);  s += __shfl_xor(s, 2);  s += __shfl_xor(s, 4);
  s += __shfl_xor(s, 8);  s += __shfl_xor(s, 16); s += __shfl_xor(s, 32);
  if (lane == 0) r2[id] = 1.0f / (1.0f + __expf(-(s + br2[e])));
}

// ---------------- kernel 6b: premix depthwise taps (fold BN scale in) --------
// kwbuf[plane][12] = {k0*sc .. k8*sc, bias, 0, 0}
__global__ __launch_bounds__(256) void k_kwmix(const float* __restrict__ r2,
    const float* __restrict__ w2, const float* __restrict__ sc2,
    const float* __restrict__ bi2, float* __restrict__ kwbuf) {
  int i = blockIdx.x * 256 + threadIdx.x;
  if (i >= B_ * HIDD) return;
  int b = i / HIDD, c = i - b * HIDD;
  float rr[NE];
#pragma unroll
  for (int e = 0; e < NE; ++e) rr[e] = r2[b * 8 + e];
  float sc = sc2[c];
  float out[12];
#pragma unroll
  for (int k = 0; k < 9; ++k) {
    float s = 0.f;
#pragma unroll
    for (int e = 0; e < NE; ++e) s += rr[e] * w2[((size_t)e * HIDD + c) * 9 + k];
    out[k] = s * sc;
  }
  out[9] = bi2[c]; out[10] = 0.f; out[11] = 0.f;
#pragma unroll
  for (int k = 0; k < 12; ++k) kwbuf[(size_t)i * 12 + k] = out[k];
}

// -- load 10-wide window of one image row into regs (row = 56 px = 7 octets) --
__device__ __forceinline__ void load_row10(const unsigned short* __restrict__ row,
                                           int w0, float* o) {
  int4 v = *(const int4*)(row + w0);
  unsigned short e[8]; __builtin_memcpy(e, &v, 16);
  o[0] = (w0 > 0) ? bf2f(row[w0 - 1]) : 0.f;
#pragma unroll
  for (int i = 0; i < 8; ++i) o[1 + i] = bf2f(e[i]);
  o[9] = (w0 < 48) ? bf2f(row[w0 + 8]) : 0.f;
}

// ---------------- kernel 7: FUSED depthwise3x3 + project GEMM + BN + residual
// For each K-chunk (64 channels), each stencil task (channel, 8-px octet)
// loads 3 halo rows of post-expand y from global into registers, applies the
// BN-folded depthwise taps + ReLU6, and scatters bf16 results into Bs.
// z is never materialized. out[b][o][p] = bn3(sum_h w3c[o][h]*z[h][p]) + x.
__global__ __launch_bounds__(384) void k_project2(const unsigned short* __restrict__ y,
    const unsigned short* __restrict__ w3c, const float* __restrict__ kwbuf,
    const float* __restrict__ sc3, const float* __restrict__ bi3,
    const float* __restrict__ x, float* __restrict__ out) {
  __shared__ unsigned short As[96 * 72];
  __shared__ unsigned short Bs[64 * 72];
  int t = threadIdx.x;
  int p0 = blockIdx.x * 64, b = blockIdx.z;
  const unsigned short* ag = w3c + (size_t)b * 55296;
  const unsigned short* yb = y + (size_t)b * HIDD * NP;
  const float* kwb = kwbuf + (size_t)b * HIDD * 12;
  int lane = t & 63, wv = t >> 6;
  int m = lane & 15, q = lane >> 4;
  f32x4 acc[4];
#pragma unroll
  for (int nt = 0; nt < 4; ++nt) acc[nt] = 0.f;
  for (int c0 = 0; c0 < HIDD; c0 += 64) {
    __syncthreads();
    // stage A (w3c chunk)
    for (int j = t; j < 768; j += 384) {
      int r = j >> 3, ch = j & 7;
      *(int4*)(As + r * 72 + ch * 8) = *(const int4*)(ag + (size_t)r * 576 + c0 + ch * 8);
    }
    // stencil tasks: 512 = 64 channels x 8 octets
    for (int task = t; task < 512; task += 384) {
      int c = task >> 3, j = task & 7;
      int px0 = p0 + j * 8;            // 8-aligned -> single image row
      int h = px0 / 56, w0 = px0 - h * 56;
      const unsigned short* yrow = yb + (size_t)(c0 + c) * NP;
      const float* kw = kwb + (size_t)(c0 + c) * 12;
      float4 ka = *(const float4*)kw;
      float4 kb = *(const float4*)(kw + 4);
      float4 kc = *(const float4*)(kw + 8);
      float rm[10], r0[10], rp[10];
#pragma unroll
      for (int i = 0; i < 10; ++i) { rm[i] = 0.f; rp[i] = 0.f; }
      load_row10(yrow + h * 56, w0, r0);
      if (h > 0)  load_row10(yrow + (h - 1) * 56, w0, rm);
      if (h < 55) load_row10(yrow + (h + 1) * 56, w0, rp);
#pragma unroll
      for (int i = 0; i < 8; ++i) {
        float o = rm[i] * ka.x + rm[i + 1] * ka.y + rm[i + 2] * ka.z
                + r0[i] * ka.w + r0[i + 1] * kb.x + r0[i + 2] * kb.y
                + rp[i] * kb.z + rp[i + 1] * kb.w + rp[i + 2] * kc.x + kc.y;
        o = fminf(fmaxf(o, 0.f), 6.f);
        Bs[(j * 8 + i) * 72 + c] = f2bf(o);
      }
    }
    __syncthreads();
#pragma unroll
    for (int kk = 0; kk < 2; ++kk) {
      bf16x8 af = *(const bf16x8*)(As + (wv * 16 + m) * 72 + kk * 32 + q * 8);
#pragma unroll
      for (int nt = 0; nt < 4; ++nt) {
        bf16x8 bfb = *(const bf16x8*)(Bs + (nt * 16 + m) * 72 + kk * 32 + q * 8);
        acc[nt] = __builtin_amdgcn_mfma_f32_16x16x32_bf16(af, bfb, acc[nt], 0, 0, 0);
      }
    }
  }
#pragma unroll
  for (int i = 0; i < 4; ++i) {
    int o = wv * 16 + q * 4 + i;
    float sc = sc3[o], bb = bi3[o];
    size_t base = ((size_t)(b * COUT + o)) * NP + p0;
#pragma unroll
    for (int nt = 0; nt < 4; ++nt) {
      float v = acc[nt][i] * sc + bb + x[base + nt * 16 + m];
      out[base + nt * 16 + m] = v;
    }
  }
}

// ---------------- workspace layout (bytes) -----------------------------------
#define OFF_XT    ((size_t)0)           // 19267584 (dead after expand; kwbuf aliases)
#define OFF_Y     ((size_t)19267584)    // 115605504
#define OFF_W1C   ((size_t)134873088)   // 3538944
#define OFF_W3C   ((size_t)138412032)   // 3538944
#define OFF_XMEAN ((size_t)141950976)   // 12288   (zeroed)
#define OFF_YSUM  ((size_t)141963264)   // 73728   (zeroed)
#define OFF_R1    ((size_t)142036992)   // 1024
#define OFF_RBLK  ((size_t)142038016)   // 1024
#define OFF_R2    ((size_t)142039040)   // 1024
#define OFF_SC1   ((size_t)142040064)   // 2304
#define OFF_BI1   ((size_t)142042368)   // 2304
#define OFF_SC2   ((size_t)142044672)   // 2304
#define OFF_BI2   ((size_t)142046976)   // 2304
#define OFF_SC3   ((size_t)142049280)   // 384
#define OFF_BI3   ((size_t)142049664)   // 384
#define OFF_KW    OFF_XT                // 884736 (aliases xt after expand)

extern "C" void kernel_launch(void* const* d_in, const int* in_sizes, int n_in,
                              void* d_out, int out_size, void* d_ws, size_t ws_size,
                              hipStream_t stream) {
  const float* x   = (const float*)d_in[0];
  const float* wr1 = (const float*)d_in[1];
  const float* br1 = (const float*)d_in[2];
  const float* w1  = (const float*)d_in[3];
  const float* g1  = (const float*)d_in[4];
  const float* bt1 = (const float*)d_in[5];
  const float* m1  = (const float*)d_in[6];
  const float* v1  = (const float*)d_in[7];
  const float* wr2 = (const float*)d_in[8];
  const float* br2 = (const float*)d_in[9];
  const float* w2  = (const float*)d_in[10];
  const float* g2  = (const float*)d_in[11];
  const float* bt2 = (const float*)d_in[12];
  const float* m2  = (const float*)d_in[13];
  const float* v2  = (const float*)d_in[14];
  const float* w3  = (const float*)d_in[15];
  const float* g3  = (const float*)d_in[16];
  const float* bt3 = (const float*)d_in[17];
  const float* m3  = (const float*)d_in[18];
  const float* v3  = (const float*)d_in[19];
  const float* wr3 = (const float*)d_in[20];
  const float* br3 = (const float*)d_in[21];
  float* out = (float*)d_out;
  char* ws = (char*)d_ws;

  unsigned short* xt   = (unsigned short*)(ws + OFF_XT);
  unsigned short* y    = (unsigned short*)(ws + OFF_Y);
  unsigned short* w1c  = (unsigned short*)(ws + OFF_W1C);
  unsigned short* w3c  = (unsigned short*)(ws + OFF_W3C);
  float* xmean = (float*)(ws + OFF_XMEAN);
  float* ysum  = (float*)(ws + OFF_YSUM);
  float* r1    = (float*)(ws + OFF_R1);
  float* rblk  = (float*)(ws + OFF_RBLK);
  float* r2    = (float*)(ws + OFF_R2);
  float* sc1   = (float*)(ws + OFF_SC1);
  float* bi1   = (float*)(ws + OFF_BI1);
  float* sc2   = (float*)(ws + OFF_SC2);
  float* bi2   = (float*)(ws + OFF_BI2);
  float* sc3   = (float*)(ws + OFF_SC3);
  float* bi3   = (float*)(ws + OFF_BI3);
  float* kwbuf = (float*)(ws + OFF_KW);

  // zero the atomic-accumulation buffers (xmean + ysum are contiguous)
  hipMemsetAsync(ws + OFF_XMEAN, 0, 12288 + 73728, stream);

  k_transpose<<<32 * 49, 256, 0, stream>>>(x, xt, xmean);
  k_router1<<<512, 64, 0, stream>>>(xmean, wr1, br1, wr3, br3, r1, rblk);
  k_bnprep<<<5, 256, 0, stream>>>(g1, bt1, m1, v1, g2, bt2, m2, v2, g3, bt3, m3, v3,
                                  sc1, bi1, sc2, bi2, sc3, bi3);
  k_mixw<<<432, 256, 0, stream>>>(w1, r1, w1c, w3, rblk, w3c);
  k_expand<<<dim3(49, 9, 32), 256, 0, stream>>>(xt, w1c, sc1, bi1, y, ysum);
  k_router2<<<256, 64, 0, stream>>>(ysum, wr2, br2, r2);
  k_kwmix<<<72, 256, 0, stream>>>(r2, w2, sc2, bi2, kwbuf);
  k_project2<<<dim3(49, 1, 32), 384, 0, stream>>>(y, w3c, kwbuf, sc3, bi3, x, out);
}

// Round 4
// 340.024 us; speedup vs baseline: 1.1169x; 1.1169x over previous
//
#include <hip/hip_runtime.h>
#include <hip/hip_bf16.h>

#define B_   32
#define CIN  96
#define COUT 96
#define NP   3136
#define NE   8
#define HIDD 576

typedef short bf16x8 __attribute__((ext_vector_type(8)));
typedef float f32x4 __attribute__((ext_vector_type(4)));

__device__ __forceinline__ unsigned short f2bf(float f) {
  __hip_bfloat16 h = __float2bfloat16(f);
  unsigned short u; __builtin_memcpy(&u, &h, 2); return u;
}
__device__ __forceinline__ float bf2f(unsigned short u) {
  unsigned int v = ((unsigned int)u) << 16;
  float f; __builtin_memcpy(&f, &v, 4); return f;
}

// ---------------- kernel 1: transpose x -> x_t[b][p][c] bf16, + channel sums --
__global__ __launch_bounds__(256) void k_transpose(const float* __restrict__ x,
                                                   unsigned short* __restrict__ xt,
                                                   float* __restrict__ xmean) {
  __shared__ float tile[CIN][65];
  int bi = blockIdx.x; int b = bi / 49, pt = bi % 49; int p0 = pt * 64;
  int t = threadIdx.x;
  for (int j = t; j < CIN * 64; j += 256) {
    int c = j >> 6, pi = j & 63;
    tile[c][pi] = x[((size_t)(b * CIN + c)) * NP + p0 + pi];
  }
  __syncthreads();
  if (t < CIN) {
    float s = 0.f;
    for (int i = 0; i < 64; ++i) s += tile[t][i];
    atomicAdd(xmean + b * CIN + t, s);
  }
  for (int j = t; j < 64 * CIN; j += 256) {
    int p = j / CIN, c = j % CIN;
    xt[((size_t)(b * NP + p0 + p)) * CIN + c] = f2bf(tile[c][p]);
  }
}

// ---------------- kernel 2: routers r1 (expand) and r_blk (project) ----------
__global__ __launch_bounds__(64) void k_router1(const float* __restrict__ xmean,
    const float* __restrict__ wr1, const float* __restrict__ br1,
    const float* __restrict__ wr3, const float* __restrict__ br3,
    float* __restrict__ r1, float* __restrict__ rblk) {
  int bi = blockIdx.x; int lane = threadIdx.x;
  const float* wr; const float* br; float* dst; int id;
  if (bi < 256) { wr = wr1; br = br1; dst = r1;   id = bi; }
  else          { wr = wr3; br = br3; dst = rblk; id = bi - 256; }
  int b = id >> 3, e = id & 7;
  float s = 0.f;
  for (int c = lane; c < CIN; c += 64)
    s += xmean[b * CIN + c] * (1.0f / NP) * wr[e * CIN + c];
  s += __shfl_xor(s, 1);  s += __shfl_xor(s, 2);  s += __shfl_xor(s, 4);
  s += __shfl_xor(s, 8);  s += __shfl_xor(s, 16); s += __shfl_xor(s, 32);
  if (lane == 0) dst[id] = 1.0f / (1.0f + __expf(-(s + br[e])));
}

// ---------------- kernel 3: BN scale/bias precompute -------------------------
__global__ __launch_bounds__(256) void k_bnprep(
    const float* g1, const float* bt1, const float* m1, const float* v1,
    const float* g2, const float* bt2, const float* m2, const float* v2,
    const float* g3, const float* bt3, const float* m3, const float* v3,
    float* sc1, float* bi1, float* sc2, float* bi2, float* sc3, float* bi3) {
  int i = blockIdx.x * 256 + threadIdx.x;
  if (i < HIDD) {
    float s = g1[i] * rsqrtf(v1[i] + 1e-5f); sc1[i] = s; bi1[i] = bt1[i] - m1[i] * s;
  } else if (i < 2 * HIDD) {
    int c = i - HIDD;
    float s = g2[c] * rsqrtf(v2[c] + 1e-5f); sc2[c] = s; bi2[c] = bt2[c] - m2[c] * s;
  } else if (i < 2 * HIDD + COUT) {
    int c = i - 2 * HIDD;
    float s = g3[c] * rsqrtf(v3[c] + 1e-5f); sc3[c] = s; bi3[c] = bt3[c] - m3[c] * s;
  }
}

// ---------------- kernel 4: mix expert weights -> bf16 -----------------------
__global__ __launch_bounds__(256) void k_mixw(
    const float* __restrict__ w1, const float* __restrict__ r1, unsigned short* __restrict__ w1c,
    const float* __restrict__ w3, const float* __restrict__ rblk, unsigned short* __restrict__ w3c) {
  __shared__ float rsh[256];
  int bi = blockIdx.x; int t = threadIdx.x;
  const float* w; const float* r; unsigned short* dst; int oc0;
  if (bi < 216) { w = w1; r = r1;   dst = w1c; oc0 = bi * 256; }
  else          { w = w3; r = rblk; dst = w3c; oc0 = (bi - 216) * 256; }
  rsh[t] = r[t];
  __syncthreads();
  int oc = oc0 + t;
  float wv[NE];
#pragma unroll
  for (int e = 0; e < NE; ++e) wv[e] = w[(size_t)e * 55296 + oc];
  for (int b = 0; b < B_; ++b) {
    float a = 0.f;
#pragma unroll
    for (int e = 0; e < NE; ++e) a += rsh[b * 8 + e] * wv[e];
    dst[(size_t)b * 55296 + oc] = f2bf(a);
  }
}

// ---------------- kernel 5: expand GEMM + BN + ReLU6 + ysum, y in [b][p][h] --
// y2[b][p][o] = relu6(bn1( sum_c w1c[b][o][c] * x_t[b][p][c] ))
__global__ __launch_bounds__(256) void k_expand2(const unsigned short* __restrict__ xt,
    const unsigned short* __restrict__ w1c, const float* __restrict__ sc1,
    const float* __restrict__ bi1, unsigned short* __restrict__ y2,
    float* __restrict__ ysum) {
  __shared__ unsigned short As[64 * 104];   // w1c tile; reused as transpose buf T[64][72]
  __shared__ unsigned short Bs[64 * 104];   // xt tile
  int t = threadIdx.x;
  int p0 = blockIdx.x * 64, o0 = blockIdx.y * 64, b = blockIdx.z;
  const unsigned short* ag = w1c + (size_t)b * 55296 + (size_t)o0 * 96;
  const unsigned short* bg = xt + ((size_t)b * NP + p0) * 96;
  for (int j = t; j < 768; j += 256) {
    int r = j / 12, ch = j % 12;
    *(int4*)(As + r * 104 + ch * 8) = *(const int4*)(ag + r * 96 + ch * 8);
    *(int4*)(Bs + r * 104 + ch * 8) = *(const int4*)(bg + r * 96 + ch * 8);
  }
  __syncthreads();
  int lane = t & 63, wv = t >> 6;
  int m = lane & 15, q = lane >> 4;
  f32x4 acc[4];
#pragma unroll
  for (int nt = 0; nt < 4; ++nt) acc[nt] = 0.f;
#pragma unroll
  for (int kk = 0; kk < 3; ++kk) {
    bf16x8 af = *(const bf16x8*)(As + (wv * 16 + m) * 104 + kk * 32 + q * 8);
#pragma unroll
    for (int nt = 0; nt < 4; ++nt) {
      bf16x8 bfb = *(const bf16x8*)(Bs + (nt * 16 + m) * 104 + kk * 32 + q * 8);
      acc[nt] = __builtin_amdgcn_mfma_f32_16x16x32_bf16(af, bfb, acc[nt], 0, 0, 0);
    }
  }
  __syncthreads();   // all LDS reads done; As is now free for reuse
  // epilogue: BN+ReLU6, row sums, stage bf16 tile into T[p-local][o-local]
  float sc[4], bb[4];
#pragma unroll
  for (int i = 0; i < 4; ++i) {
    int o = o0 + wv * 16 + q * 4 + i;
    sc[i] = sc1[o]; bb[i] = bi1[o];
  }
  float rs[4] = {0.f, 0.f, 0.f, 0.f};
  unsigned short* T = As;   // T stride 72 u16 (144 B, 16B-aligned rows)
#pragma unroll
  for (int nt = 0; nt < 4; ++nt) {
    unsigned short pk[4];
#pragma unroll
    for (int i = 0; i < 4; ++i) {
      float v = acc[nt][i] * sc[i] + bb[i];
      v = fminf(fmaxf(v, 0.f), 6.f);
      rs[i] += v;
      pk[i] = f2bf(v);
    }
    uint2 pv; __builtin_memcpy(&pv, pk, 8);
    *(uint2*)(T + (nt * 16 + m) * 72 + wv * 16 + q * 4) = pv;
  }
#pragma unroll
  for (int i = 0; i < 4; ++i) {
    float r = rs[i];
    r += __shfl_xor(r, 1); r += __shfl_xor(r, 2);
    r += __shfl_xor(r, 4); r += __shfl_xor(r, 8);
    if (m == 0) atomicAdd(ysum + b * HIDD + o0 + wv * 16 + q * 4 + i, r);
  }
  __syncthreads();
  // coalesced write: y2[b][p0+r][o0 .. o0+63]
  for (int j = t; j < 512; j += 256) {
    int r = j >> 3, ch = j & 7;
    *(int4*)(y2 + ((size_t)(b * NP + p0 + r)) * 576 + o0 + ch * 8) =
        *(const int4*)(T + r * 72 + ch * 8);
  }
}

// ---------------- kernel 6: router r2 (depthwise) ----------------------------
__global__ __launch_bounds__(64) void k_router2(const float* __restrict__ ysum,
    const float* __restrict__ wr2, const float* __restrict__ br2, float* __restrict__ r2) {
  int id = blockIdx.x; int lane = threadIdx.x;
  int b = id >> 3, e = id & 7;
  float s = 0.f;
  for (int h = lane; h < HIDD; h += 64)
    s += ysum[b * HIDD + h] * (1.0f / NP) * wr2[e * HIDD + h];
  s += __shfl_xor(s, 1);  s += __shfl_xor(s, 2);  s += __shfl_xor(s, 4);
  s += __shfl_xor(s, 8);  s += __shfl_xor(s, 16); s += __shfl_xor(s, 32);
  if (lane == 0) r2[id] = 1.0f / (1.0f + __expf(-(s + br2[e])));
}

// ---------------- kernel 6b: premix depthwise taps, layout kwt[b][tap][c] ----
// kwt[b][k][c] = kw_k(c)*sc2[c] for k=0..8;  kwt[b][9][c] = bias
__global__ __launch_bounds__(256) void k_kwmix2(const float* __restrict__ r2,
    const float* __restrict__ w2, const float* __restrict__ sc2,
    const float* __restrict__ bi2, float* __restrict__ kwt) {
  int i = blockIdx.x * 256 + threadIdx.x;
  if (i >= B_ * HIDD) return;
  int b = i / HIDD, c = i - b * HIDD;
  float rr[NE];
#pragma unroll
  for (int e = 0; e < NE; ++e) rr[e] = r2[b * 8 + e];
  float sc = sc2[c];
  float* dst = kwt + (size_t)b * 5760 + c;
#pragma unroll
  for (int k = 0; k < 9; ++k) {
    float s = 0.f;
#pragma unroll
    for (int e = 0; e < NE; ++e) s += rr[e] * w2[((size_t)e * HIDD + c) * 9 + k];
    dst[k * 576] = s * sc;
  }
  dst[9 * 576] = bi2[c];
}

// ---------------- kernel 7: depthwise 3x3 in [p][h] layout, column-sliding ---
// thread = one channel (lanes contiguous in c -> every access 128B coalesced).
// block = (h row, c-group of 192, b). 3 loads + 9 FMA per output, no LDS.
__global__ __launch_bounds__(192) void k_dwise3(const unsigned short* __restrict__ y2,
    const float* __restrict__ kwt, unsigned short* __restrict__ z2) {
  int h = blockIdx.x, cg = blockIdx.y, b = blockIdx.z;
  int c = cg * 192 + threadIdx.x;
  const float* kp = kwt + (size_t)b * 5760 + c;
  float k0 = kp[0],        k1 = kp[576],      k2 = kp[2 * 576],
        k3 = kp[3 * 576],  k4 = kp[4 * 576],  k5 = kp[5 * 576],
        k6 = kp[6 * 576],  k7 = kp[7 * 576],  k8 = kp[8 * 576],
        bias = kp[9 * 576];
  const unsigned short* base = y2 + ((size_t)(b * NP + h * 56)) * 576 + c;
  unsigned short* zo = z2 + ((size_t)(b * NP + h * 56)) * 576 + c;
  bool hu = h > 0, hd = h < 55;
  float fu = hu ? 1.f : 0.f, fd = hd ? 1.f : 0.f;
  const unsigned short* upr = hu ? (base - 56 * 576) : base;  // always-valid addr
  const unsigned short* dnr = hd ? (base + 56 * 576) : base;
  // (row)(col): m=w-1, c=w, p=w+1 for rows u(p-56)/m(p)/d(p+56)
  float um = 0.f, mm = 0.f, dm = 0.f;
  float uc = bf2f(upr[0]) * fu, mc = bf2f(base[0]), dc = bf2f(dnr[0]) * fd;
  float upc = bf2f(upr[576]) * fu, mpc = bf2f(base[576]), dpc = bf2f(dnr[576]) * fd;
#pragma unroll 8
  for (int w = 0; w < 56; ++w) {
    float un = 0.f, mn = 0.f, dn2 = 0.f;
    if (w < 54) {
      int off = (w + 2) * 576;
      un = bf2f(upr[off]) * fu; mn = bf2f(base[off]); dn2 = bf2f(dnr[off]) * fd;
    }
    float o = um * k0 + uc * k1 + upc * k2
            + mm * k3 + mc * k4 + mpc * k5
            + dm * k6 + dc * k7 + dpc * k8 + bias;
    o = fminf(fmaxf(o, 0.f), 6.f);
    zo[w * 576] = f2bf(o);
    um = uc; uc = upc; upc = un;
    mm = mc; mc = mpc; mpc = mn;
    dm = dc; dc = dpc; dpc = dn2;
  }
}

// ---------------- kernel 8: project GEMM + BN + residual (z in [p][h]) -------
// out[b][o][p] = bn3( sum_h w3c[b][o][h] * z2[b][p][h] ) + x[b][o][p]
// B-stage is now a straight int4 copy (K contiguous) -> no scatter conflicts.
__global__ __launch_bounds__(384) void k_project3(const unsigned short* __restrict__ z2,
    const unsigned short* __restrict__ w3c, const float* __restrict__ sc3,
    const float* __restrict__ bi3, const float* __restrict__ x, float* __restrict__ out) {
  __shared__ unsigned short As[96 * 72];
  __shared__ unsigned short Bs[64 * 72];
  int t = threadIdx.x;
  int p0 = blockIdx.x * 64, b = blockIdx.z;
  const unsigned short* ag = w3c + (size_t)b * 55296;
  const unsigned short* zb = z2 + ((size_t)(b * NP + p0)) * 576;
  int lane = t & 63, wv = t >> 6;
  int m = lane & 15, q = lane >> 4;
  f32x4 acc[4];
#pragma unroll
  for (int nt = 0; nt < 4; ++nt) acc[nt] = 0.f;
  for (int c0 = 0; c0 < HIDD; c0 += 64) {
    __syncthreads();
    for (int j = t; j < 768; j += 384) {
      int r = j >> 3, ch = j & 7;
      *(int4*)(As + r * 72 + ch * 8) = *(const int4*)(ag + (size_t)r * 576 + c0 + ch * 8);
    }
    for (int j = t; j < 512; j += 384) {
      int r = j >> 3, ch = j & 7;
      *(int4*)(Bs + r * 72 + ch * 8) = *(const int4*)(zb + (size_t)r * 576 + c0 + ch * 8);
    }
    __syncthreads();
#pragma unroll
    for (int kk = 0; kk < 2; ++kk) {
      bf16x8 af = *(const bf16x8*)(As + (wv * 16 + m) * 72 + kk * 32 + q * 8);
#pragma unroll
      for (int nt = 0; nt < 4; ++nt) {
        bf16x8 bfb = *(const bf16x8*)(Bs + (nt * 16 + m) * 72 + kk * 32 + q * 8);
        acc[nt] = __builtin_amdgcn_mfma_f32_16x16x32_bf16(af, bfb, acc[nt], 0, 0, 0);
      }
    }
  }
#pragma unroll
  for (int i = 0; i < 4; ++i) {
    int o = wv * 16 + q * 4 + i;
    float sc = sc3[o], bb = bi3[o];
    size_t base = ((size_t)(b * COUT + o)) * NP + p0;
#pragma unroll
    for (int nt = 0; nt < 4; ++nt) {
      float v = acc[nt][i] * sc + bb + x[base + nt * 16 + m];
      out[base + nt * 16 + m] = v;
    }
  }
}

// ---------------- workspace layout (bytes) -----------------------------------
#define OFF_XT    ((size_t)0)           // 19267584 (dead after expand)
#define OFF_KWT   OFF_XT                // 737280, aliases xt (written after expand)
#define OFF_Y     ((size_t)19267584)    // 115605504  y2 [b][p][h] bf16
#define OFF_Z     ((size_t)134873088)   // 115605504  z2 [b][p][h] bf16
#define OFF_W1C   ((size_t)250478592)   // 3538944
#define OFF_W3C   ((size_t)254017536)   // 3538944
#define OFF_XMEAN ((size_t)257556480)   // 12288   (zeroed)
#define OFF_YSUM  ((size_t)257568768)   // 73728   (zeroed)
#define OFF_R1    ((size_t)257642496)   // 1024
#define OFF_RBLK  ((size_t)257643520)   // 1024
#define OFF_R2    ((size_t)257644544)   // 1024
#define OFF_SC1   ((size_t)257645568)   // 2304
#define OFF_BI1   ((size_t)257647872)   // 2304
#define OFF_SC2   ((size_t)257650176)   // 2304
#define OFF_BI2   ((size_t)257652480)   // 2304
#define OFF_SC3   ((size_t)257654784)   // 384
#define OFF_BI3   ((size_t)257655168)   // 384  -> total 257655552 B (~245.8 MiB)

extern "C" void kernel_launch(void* const* d_in, const int* in_sizes, int n_in,
                              void* d_out, int out_size, void* d_ws, size_t ws_size,
                              hipStream_t stream) {
  const float* x   = (const float*)d_in[0];
  const float* wr1 = (const float*)d_in[1];
  const float* br1 = (const float*)d_in[2];
  const float* w1  = (const float*)d_in[3];
  const float* g1  = (const float*)d_in[4];
  const float* bt1 = (const float*)d_in[5];
  const float* m1  = (const float*)d_in[6];
  const float* v1  = (const float*)d_in[7];
  const float* wr2 = (const float*)d_in[8];
  const float* br2 = (const float*)d_in[9];
  const float* w2  = (const float*)d_in[10];
  const float* g2  = (const float*)d_in[11];
  const float* bt2 = (const float*)d_in[12];
  const float* m2  = (const float*)d_in[13];
  const float* v2  = (const float*)d_in[14];
  const float* w3  = (const float*)d_in[15];
  const float* g3  = (const float*)d_in[16];
  const float* bt3 = (const float*)d_in[17];
  const float* m3  = (const float*)d_in[18];
  const float* v3  = (const float*)d_in[19];
  const float* wr3 = (const float*)d_in[20];
  const float* br3 = (const float*)d_in[21];
  float* out = (float*)d_out;
  char* ws = (char*)d_ws;

  unsigned short* xt   = (unsigned short*)(ws + OFF_XT);
  unsigned short* y2   = (unsigned short*)(ws + OFF_Y);
  unsigned short* z2   = (unsigned short*)(ws + OFF_Z);
  unsigned short* w1c  = (unsigned short*)(ws + OFF_W1C);
  unsigned short* w3c  = (unsigned short*)(ws + OFF_W3C);
  float* xmean = (float*)(ws + OFF_XMEAN);
  float* ysum  = (float*)(ws + OFF_YSUM);
  float* r1    = (float*)(ws + OFF_R1);
  float* rblk  = (float*)(ws + OFF_RBLK);
  float* r2    = (float*)(ws + OFF_R2);
  float* sc1   = (float*)(ws + OFF_SC1);
  float* bi1   = (float*)(ws + OFF_BI1);
  float* sc2   = (float*)(ws + OFF_SC2);
  float* bi2   = (float*)(ws + OFF_BI2);
  float* sc3   = (float*)(ws + OFF_SC3);
  float* bi3   = (float*)(ws + OFF_BI3);
  float* kwt   = (float*)(ws + OFF_KWT);

  // zero the atomic-accumulation buffers (xmean + ysum are contiguous)
  hipMemsetAsync(ws + OFF_XMEAN, 0, 12288 + 73728, stream);

  k_transpose<<<32 * 49, 256, 0, stream>>>(x, xt, xmean);
  k_router1<<<512, 64, 0, stream>>>(xmean, wr1, br1, wr3, br3, r1, rblk);
  k_bnprep<<<5, 256, 0, stream>>>(g1, bt1, m1, v1, g2, bt2, m2, v2, g3, bt3, m3, v3,
                                  sc1, bi1, sc2, bi2, sc3, bi3);
  k_mixw<<<432, 256, 0, stream>>>(w1, r1, w1c, w3, rblk, w3c);
  k_expand2<<<dim3(49, 9, 32), 256, 0, stream>>>(xt, w1c, sc1, bi1, y2, ysum);
  k_router2<<<256, 64, 0, stream>>>(ysum, wr2, br2, r2);
  k_kwmix2<<<72, 256, 0, stream>>>(r2, w2, sc2, bi2, kwt);
  k_dwise3<<<dim3(56, 3, 32), 192, 0, stream>>>(y2, kwt, z2);
  k_project3<<<dim3(49, 1, 32), 384, 0, stream>>>(z2, w3c, sc3, bi3, x, out);
}

// Round 5
// 327.674 us; speedup vs baseline: 1.1590x; 1.0377x over previous
//
#include <hip/hip_runtime.h>
#include <hip/hip_bf16.h>

#define B_   32
#define CIN  96
#define COUT 96
#define NP   3136
#define NE   8
#define HIDD 576

typedef short bf16x8 __attribute__((ext_vector_type(8)));
typedef float f32x4 __attribute__((ext_vector_type(4)));

__device__ __forceinline__ unsigned short f2bf(float f) {
  __hip_bfloat16 h = __float2bfloat16(f);
  unsigned short u; __builtin_memcpy(&u, &h, 2); return u;
}
__device__ __forceinline__ float bf2f(unsigned short u) {
  unsigned int v = ((unsigned int)u) << 16;
  float f; __builtin_memcpy(&f, &v, 4); return f;
}
__device__ __forceinline__ float u2f(unsigned int v) {
  float f; __builtin_memcpy(&f, &v, 4); return f;
}

// ---------------- kernel 1: transpose x -> x_t[b][p][c] bf16, + channel sums --
__global__ __launch_bounds__(256) void k_transpose(const float* __restrict__ x,
                                                   unsigned short* __restrict__ xt,
                                                   float* __restrict__ xmean) {
  __shared__ float tile[CIN][65];
  int bi = blockIdx.x; int b = bi / 49, pt = bi % 49; int p0 = pt * 64;
  int t = threadIdx.x;
  for (int j = t; j < CIN * 64; j += 256) {
    int c = j >> 6, pi = j & 63;
    tile[c][pi] = x[((size_t)(b * CIN + c)) * NP + p0 + pi];
  }
  __syncthreads();
  if (t < CIN) {
    float s = 0.f;
    for (int i = 0; i < 64; ++i) s += tile[t][i];
    atomicAdd(xmean + b * CIN + t, s);
  }
  for (int j = t; j < 64 * CIN; j += 256) {
    int p = j / CIN, c = j % CIN;
    xt[((size_t)(b * NP + p0 + p)) * CIN + c] = f2bf(tile[c][p]);
  }
}

// ---------------- kernel 2: routers r1 (expand) and r_blk (project) ----------
__global__ __launch_bounds__(64) void k_router1(const float* __restrict__ xmean,
    const float* __restrict__ wr1, const float* __restrict__ br1,
    const float* __restrict__ wr3, const float* __restrict__ br3,
    float* __restrict__ r1, float* __restrict__ rblk) {
  int bi = blockIdx.x; int lane = threadIdx.x;
  const float* wr; const float* br; float* dst; int id;
  if (bi < 256) { wr = wr1; br = br1; dst = r1;   id = bi; }
  else          { wr = wr3; br = br3; dst = rblk; id = bi - 256; }
  int b = id >> 3, e = id & 7;
  float s = 0.f;
  for (int c = lane; c < CIN; c += 64)
    s += xmean[b * CIN + c] * (1.0f / NP) * wr[e * CIN + c];
  s += __shfl_xor(s, 1);  s += __shfl_xor(s, 2);  s += __shfl_xor(s, 4);
  s += __shfl_xor(s, 8);  s += __shfl_xor(s, 16); s += __shfl_xor(s, 32);
  if (lane == 0) dst[id] = 1.0f / (1.0f + __expf(-(s + br[e])));
}

// ---------------- kernel 3: BN scale/bias precompute -------------------------
__global__ __launch_bounds__(256) void k_bnprep(
    const float* g1, const float* bt1, const float* m1, const float* v1,
    const float* g2, const float* bt2, const float* m2, const float* v2,
    const float* g3, const float* bt3, const float* m3, const float* v3,
    float* sc1, float* bi1, float* sc2, float* bi2, float* sc3, float* bi3) {
  int i = blockIdx.x * 256 + threadIdx.x;
  if (i < HIDD) {
    float s = g1[i] * rsqrtf(v1[i] + 1e-5f); sc1[i] = s; bi1[i] = bt1[i] - m1[i] * s;
  } else if (i < 2 * HIDD) {
    int c = i - HIDD;
    float s = g2[c] * rsqrtf(v2[c] + 1e-5f); sc2[c] = s; bi2[c] = bt2[c] - m2[c] * s;
  } else if (i < 2 * HIDD + COUT) {
    int c = i - 2 * HIDD;
    float s = g3[c] * rsqrtf(v3[c] + 1e-5f); sc3[c] = s; bi3[c] = bt3[c] - m3[c] * s;
  }
}

// ---------------- kernel 4: mix expert weights -> bf16 -----------------------
__global__ __launch_bounds__(256) void k_mixw(
    const float* __restrict__ w1, const float* __restrict__ r1, unsigned short* __restrict__ w1c,
    const float* __restrict__ w3, const float* __restrict__ rblk, unsigned short* __restrict__ w3c) {
  __shared__ float rsh[256];
  int bi = blockIdx.x; int t = threadIdx.x;
  const float* w; const float* r; unsigned short* dst; int oc0;
  if (bi < 216) { w = w1; r = r1;   dst = w1c; oc0 = bi * 256; }
  else          { w = w3; r = rblk; dst = w3c; oc0 = (bi - 216) * 256; }
  rsh[t] = r[t];
  __syncthreads();
  int oc = oc0 + t;
  float wv[NE];
#pragma unroll
  for (int e = 0; e < NE; ++e) wv[e] = w[(size_t)e * 55296 + oc];
  for (int b = 0; b < B_; ++b) {
    float a = 0.f;
#pragma unroll
    for (int e = 0; e < NE; ++e) a += rsh[b * 8 + e] * wv[e];
    dst[(size_t)b * 55296 + oc] = f2bf(a);
  }
}

// ---------------- kernel 5: expand GEMM + BN + ReLU6 + ysum, y in [b][p][h] --
__global__ __launch_bounds__(256) void k_expand2(const unsigned short* __restrict__ xt,
    const unsigned short* __restrict__ w1c, const float* __restrict__ sc1,
    const float* __restrict__ bi1, unsigned short* __restrict__ y2,
    float* __restrict__ ysum) {
  __shared__ unsigned short As[64 * 104];   // w1c tile; reused as transpose buf T[64][72]
  __shared__ unsigned short Bs[64 * 104];   // xt tile
  int t = threadIdx.x;
  int p0 = blockIdx.x * 64, o0 = blockIdx.y * 64, b = blockIdx.z;
  const unsigned short* ag = w1c + (size_t)b * 55296 + (size_t)o0 * 96;
  const unsigned short* bg = xt + ((size_t)b * NP + p0) * 96;
  for (int j = t; j < 768; j += 256) {
    int r = j / 12, ch = j % 12;
    *(int4*)(As + r * 104 + ch * 8) = *(const int4*)(ag + r * 96 + ch * 8);
    *(int4*)(Bs + r * 104 + ch * 8) = *(const int4*)(bg + r * 96 + ch * 8);
  }
  __syncthreads();
  int lane = t & 63, wv = t >> 6;
  int m = lane & 15, q = lane >> 4;
  f32x4 acc[4];
#pragma unroll
  for (int nt = 0; nt < 4; ++nt) acc[nt] = 0.f;
#pragma unroll
  for (int kk = 0; kk < 3; ++kk) {
    bf16x8 af = *(const bf16x8*)(As + (wv * 16 + m) * 104 + kk * 32 + q * 8);
#pragma unroll
    for (int nt = 0; nt < 4; ++nt) {
      bf16x8 bfb = *(const bf16x8*)(Bs + (nt * 16 + m) * 104 + kk * 32 + q * 8);
      acc[nt] = __builtin_amdgcn_mfma_f32_16x16x32_bf16(af, bfb, acc[nt], 0, 0, 0);
    }
  }
  __syncthreads();   // all LDS reads done; As is now free for reuse
  float sc[4], bb[4];
#pragma unroll
  for (int i = 0; i < 4; ++i) {
    int o = o0 + wv * 16 + q * 4 + i;
    sc[i] = sc1[o]; bb[i] = bi1[o];
  }
  float rs[4] = {0.f, 0.f, 0.f, 0.f};
  unsigned short* T = As;   // T stride 72 u16
#pragma unroll
  for (int nt = 0; nt < 4; ++nt) {
    unsigned short pk[4];
#pragma unroll
    for (int i = 0; i < 4; ++i) {
      float v = acc[nt][i] * sc[i] + bb[i];
      v = fminf(fmaxf(v, 0.f), 6.f);
      rs[i] += v;
      pk[i] = f2bf(v);
    }
    uint2 pv; __builtin_memcpy(&pv, pk, 8);
    *(uint2*)(T + (nt * 16 + m) * 72 + wv * 16 + q * 4) = pv;
  }
#pragma unroll
  for (int i = 0; i < 4; ++i) {
    float r = rs[i];
    r += __shfl_xor(r, 1); r += __shfl_xor(r, 2);
    r += __shfl_xor(r, 4); r += __shfl_xor(r, 8);
    if (m == 0) atomicAdd(ysum + b * HIDD + o0 + wv * 16 + q * 4 + i, r);
  }
  __syncthreads();
  for (int j = t; j < 512; j += 256) {
    int r = j >> 3, ch = j & 7;
    *(int4*)(y2 + ((size_t)(b * NP + p0 + r)) * 576 + o0 + ch * 8) =
        *(const int4*)(T + r * 72 + ch * 8);
  }
}

// ---------------- kernel 6: router r2 (depthwise) ----------------------------
__global__ __launch_bounds__(64) void k_router2(const float* __restrict__ ysum,
    const float* __restrict__ wr2, const float* __restrict__ br2, float* __restrict__ r2) {
  int id = blockIdx.x; int lane = threadIdx.x;
  int b = id >> 3, e = id & 7;
  float s = 0.f;
  for (int h = lane; h < HIDD; h += 64)
    s += ysum[b * HIDD + h] * (1.0f / NP) * wr2[e * HIDD + h];
  s += __shfl_xor(s, 1);  s += __shfl_xor(s, 2);  s += __shfl_xor(s, 4);
  s += __shfl_xor(s, 8);  s += __shfl_xor(s, 16); s += __shfl_xor(s, 32);
  if (lane == 0) r2[id] = 1.0f / (1.0f + __expf(-(s + br2[e])));
}

// ---------------- kernel 6b: premix depthwise taps, layout kwt[b][tap][c] ----
__global__ __launch_bounds__(256) void k_kwmix2(const float* __restrict__ r2,
    const float* __restrict__ w2, const float* __restrict__ sc2,
    const float* __restrict__ bi2, float* __restrict__ kwt) {
  int i = blockIdx.x * 256 + threadIdx.x;
  if (i >= B_ * HIDD) return;
  int b = i / HIDD, c = i - b * HIDD;
  float rr[NE];
#pragma unroll
  for (int e = 0; e < NE; ++e) rr[e] = r2[b * 8 + e];
  float sc = sc2[c];
  float* dst = kwt + (size_t)b * 5760 + c;
#pragma unroll
  for (int k = 0; k < 9; ++k) {
    float s = 0.f;
#pragma unroll
    for (int e = 0; e < NE; ++e) s += rr[e] * w2[((size_t)e * HIDD + c) * 9 + k];
    dst[k * 576] = s * sc;
  }
  dst[9 * 576] = bi2[c];
}

// ---------------- kernel 7: depthwise 3x3 — 4ch x 2 output rows per thread ---
// thread = (b, h-pair, c-quad). uint2 vector loads (4 bf16), taps as f32x4 in
// regs, column-FIR with triple-unrolled role rotation (no window-copy movs).
__device__ __forceinline__ f32x4 cvt4(uint2 v) {
  f32x4 r;
  r[0] = u2f(v.x << 16); r[1] = u2f(v.x & 0xffff0000u);
  r[2] = u2f(v.y << 16); r[3] = u2f(v.y & 0xffff0000u);
  return r;
}
__device__ __forceinline__ uint2 pack4(f32x4 v) {
  uint2 r;
  r.x = (unsigned)f2bf(v[0]) | ((unsigned)f2bf(v[1]) << 16);
  r.y = (unsigned)f2bf(v[2]) | ((unsigned)f2bf(v[3]) << 16);
  return r;
}
__device__ __forceinline__ f32x4 clamp6(f32x4 v) {
#pragma unroll
  for (int i = 0; i < 4; ++i) v[i] = fminf(fmaxf(v[i], 0.f), 6.f);
  return v;
}

__global__ __launch_bounds__(256) void k_dwise4(const unsigned short* __restrict__ y2,
    const float* __restrict__ kwt, unsigned short* __restrict__ z2) {
  int id = blockIdx.x * 256 + threadIdx.x;          // 28 hpairs * 144 cquads * 32 b
  if (id >= 28 * 144 * 32) return;
  int cg = id % 144; int rest = id / 144;
  int hp = rest % 28; int b = rest / 28;
  int c = cg * 4, h0 = hp * 2;
  const float* kp = kwt + (size_t)b * 5760 + c;
  f32x4 tk[9], tb;
#pragma unroll
  for (int k = 0; k < 9; ++k) tk[k] = *(const f32x4*)(kp + k * 576);
  tb = *(const f32x4*)(kp + 9 * 576);
  // input rows h0-1 .. h0+2 (clamped addr; invalid rows zeroed at load)
  bool ok0 = (hp > 0), ok3 = (hp < 27);
  int r0 = ok0 ? (h0 - 1) : h0;
  int r3 = ok3 ? (h0 + 2) : (h0 + 1);
  const unsigned short* rowp[4];
  rowp[0] = y2 + ((size_t)(b * NP + r0 * 56)) * 576 + c;
  rowp[1] = y2 + ((size_t)(b * NP + h0 * 56)) * 576 + c;
  rowp[2] = y2 + ((size_t)(b * NP + (h0 + 1) * 56)) * 576 + c;
  rowp[3] = y2 + ((size_t)(b * NP + r3 * 56)) * 576 + c;
  bool rok[4] = {ok0, true, true, ok3};
  unsigned short* zr0 = z2 + ((size_t)(b * NP + h0 * 56)) * 576 + c;
  unsigned short* zr1 = zr0 + (size_t)56 * 576;

  f32x4 P[4], C[4], N[4];
#pragma unroll
  for (int j = 0; j < 4; ++j) P[j] = 0.f;

#define LOADCOL(D, col) do {                                           \
    _Pragma("unroll") for (int j = 0; j < 4; ++j) {                    \
      uint2 raw; raw.x = 0u; raw.y = 0u;                               \
      if ((col) < 56 && rok[j]) raw = *(const uint2*)(rowp[j] + (size_t)(col) * 576); \
      D[j] = cvt4(raw);                                                \
    } } while (0)

#define DSTEP(PP, CC, NN, wcur) do {                                   \
    f32x4 o0 = tb, o1 = tb;                                            \
    _Pragma("unroll") for (int jj = 0; jj < 3; ++jj) {                 \
      o0 += PP[jj] * tk[jj * 3] + CC[jj] * tk[jj * 3 + 1] + NN[jj] * tk[jj * 3 + 2]; \
      o1 += PP[jj + 1] * tk[jj * 3] + CC[jj + 1] * tk[jj * 3 + 1] + NN[jj + 1] * tk[jj * 3 + 2]; \
    }                                                                  \
    *(uint2*)(zr0 + (size_t)(wcur) * 576) = pack4(clamp6(o0));         \
    *(uint2*)(zr1 + (size_t)(wcur) * 576) = pack4(clamp6(o1));         \
    LOADCOL(PP, (wcur) + 2);                                           \
  } while (0)

  LOADCOL(C, 0);
  LOADCOL(N, 1);
  for (int w = 0; w < 54; w += 3) {
    DSTEP(P, C, N, w);
    DSTEP(C, N, P, w + 1);
    DSTEP(N, P, C, w + 2);
  }
  DSTEP(P, C, N, 54);
  DSTEP(C, N, P, 55);
#undef DSTEP
#undef LOADCOL
}

// ---------------- kernel 8: project GEMM + BN + residual (z in [p][h]) -------
// N-tile 112 (3136 = 28*112): 14 MFMA/wave/chunk, A re-staged 28x (was 49x).
__global__ __launch_bounds__(384) void k_project4(const unsigned short* __restrict__ z2,
    const unsigned short* __restrict__ w3c, const float* __restrict__ sc3,
    const float* __restrict__ bi3, const float* __restrict__ x, float* __restrict__ out) {
  __shared__ unsigned short As[96 * 72];
  __shared__ unsigned short Bs[112 * 72];
  int t = threadIdx.x;
  int p0 = blockIdx.x * 112, b = blockIdx.z;
  const unsigned short* ag = w3c + (size_t)b * 55296;
  const unsigned short* zb = z2 + ((size_t)(b * NP + p0)) * 576;
  int lane = t & 63, wv = t >> 6;
  int m = lane & 15, q = lane >> 4;
  f32x4 acc[7];
#pragma unroll
  for (int nt = 0; nt < 7; ++nt) acc[nt] = 0.f;
  for (int c0 = 0; c0 < HIDD; c0 += 64) {
    __syncthreads();
    for (int j = t; j < 768; j += 384) {
      int r = j >> 3, ch = j & 7;
      *(int4*)(As + r * 72 + ch * 8) = *(const int4*)(ag + (size_t)r * 576 + c0 + ch * 8);
    }
    for (int j = t; j < 896; j += 384) {
      int r = j >> 3, ch = j & 7;
      *(int4*)(Bs + r * 72 + ch * 8) = *(const int4*)(zb + (size_t)r * 576 + c0 + ch * 8);
    }
    __syncthreads();
#pragma unroll
    for (int kk = 0; kk < 2; ++kk) {
      bf16x8 af = *(const bf16x8*)(As + (wv * 16 + m) * 72 + kk * 32 + q * 8);
#pragma unroll
      for (int nt = 0; nt < 7; ++nt) {
        bf16x8 bfb = *(const bf16x8*)(Bs + (nt * 16 + m) * 72 + kk * 32 + q * 8);
        acc[nt] = __builtin_amdgcn_mfma_f32_16x16x32_bf16(af, bfb, acc[nt], 0, 0, 0);
      }
    }
  }
#pragma unroll
  for (int i = 0; i < 4; ++i) {
    int o = wv * 16 + q * 4 + i;
    float sc = sc3[o], bb = bi3[o];
    size_t base = ((size_t)(b * COUT + o)) * NP + p0;
#pragma unroll
    for (int nt = 0; nt < 7; ++nt) {
      float v = acc[nt][i] * sc + bb + x[base + nt * 16 + m];
      out[base + nt * 16 + m] = v;
    }
  }
}

// ---------------- workspace layout (bytes) -----------------------------------
#define OFF_XT    ((size_t)0)           // 19267584 (dead after expand)
#define OFF_KWT   OFF_XT                // 737280, aliases xt (written after expand)
#define OFF_Y     ((size_t)19267584)    // 115605504  y2 [b][p][h] bf16
#define OFF_Z     ((size_t)134873088)   // 115605504  z2 [b][p][h] bf16
#define OFF_W1C   ((size_t)250478592)   // 3538944
#define OFF_W3C   ((size_t)254017536)   // 3538944
#define OFF_XMEAN ((size_t)257556480)   // 12288   (zeroed)
#define OFF_YSUM  ((size_t)257568768)   // 73728   (zeroed)
#define OFF_R1    ((size_t)257642496)   // 1024
#define OFF_RBLK  ((size_t)257643520)   // 1024
#define OFF_R2    ((size_t)257644544)   // 1024
#define OFF_SC1   ((size_t)257645568)   // 2304
#define OFF_BI1   ((size_t)257647872)   // 2304
#define OFF_SC2   ((size_t)257650176)   // 2304
#define OFF_BI2   ((size_t)257652480)   // 2304
#define OFF_SC3   ((size_t)257654784)   // 384
#define OFF_BI3   ((size_t)257655168)   // 384

extern "C" void kernel_launch(void* const* d_in, const int* in_sizes, int n_in,
                              void* d_out, int out_size, void* d_ws, size_t ws_size,
                              hipStream_t stream) {
  const float* x   = (const float*)d_in[0];
  const float* wr1 = (const float*)d_in[1];
  const float* br1 = (const float*)d_in[2];
  const float* w1  = (const float*)d_in[3];
  const float* g1  = (const float*)d_in[4];
  const float* bt1 = (const float*)d_in[5];
  const float* m1  = (const float*)d_in[6];
  const float* v1  = (const float*)d_in[7];
  const float* wr2 = (const float*)d_in[8];
  const float* br2 = (const float*)d_in[9];
  const float* w2  = (const float*)d_in[10];
  const float* g2  = (const float*)d_in[11];
  const float* bt2 = (const float*)d_in[12];
  const float* m2  = (const float*)d_in[13];
  const float* v2  = (const float*)d_in[14];
  const float* w3  = (const float*)d_in[15];
  const float* g3  = (const float*)d_in[16];
  const float* bt3 = (const float*)d_in[17];
  const float* m3  = (const float*)d_in[18];
  const float* v3  = (const float*)d_in[19];
  const float* wr3 = (const float*)d_in[20];
  const float* br3 = (const float*)d_in[21];
  float* out = (float*)d_out;
  char* ws = (char*)d_ws;

  unsigned short* xt   = (unsigned short*)(ws + OFF_XT);
  unsigned short* y2   = (unsigned short*)(ws + OFF_Y);
  unsigned short* z2   = (unsigned short*)(ws + OFF_Z);
  unsigned short* w1c  = (unsigned short*)(ws + OFF_W1C);
  unsigned short* w3c  = (unsigned short*)(ws + OFF_W3C);
  float* xmean = (float*)(ws + OFF_XMEAN);
  float* ysum  = (float*)(ws + OFF_YSUM);
  float* r1    = (float*)(ws + OFF_R1);
  float* rblk  = (float*)(ws + OFF_RBLK);
  float* r2    = (float*)(ws + OFF_R2);
  float* sc1   = (float*)(ws + OFF_SC1);
  float* bi1   = (float*)(ws + OFF_BI1);
  float* sc2   = (float*)(ws + OFF_SC2);
  float* bi2   = (float*)(ws + OFF_BI2);
  float* sc3   = (float*)(ws + OFF_SC3);
  float* bi3   = (float*)(ws + OFF_BI3);
  float* kwt   = (float*)(ws + OFF_KWT);

  hipMemsetAsync(ws + OFF_XMEAN, 0, 12288 + 73728, stream);

  k_transpose<<<32 * 49, 256, 0, stream>>>(x, xt, xmean);
  k_router1<<<512, 64, 0, stream>>>(xmean, wr1, br1, wr3, br3, r1, rblk);
  k_bnprep<<<5, 256, 0, stream>>>(g1, bt1, m1, v1, g2, bt2, m2, v2, g3, bt3, m3, v3,
                                  sc1, bi1, sc2, bi2, sc3, bi3);
  k_mixw<<<432, 256, 0, stream>>>(w1, r1, w1c, w3, rblk, w3c);
  k_expand2<<<dim3(49, 9, 32), 256, 0, stream>>>(xt, w1c, sc1, bi1, y2, ysum);
  k_router2<<<256, 64, 0, stream>>>(ysum, wr2, br2, r2);
  k_kwmix2<<<72, 256, 0, stream>>>(r2, w2, sc2, bi2, kwt);
  k_dwise4<<<504, 256, 0, stream>>>(y2, kwt, z2);
  k_project4<<<dim3(28, 1, 32), 384, 0, stream>>>(z2, w3c, sc3, bi3, x, out);
}